// Round 4
// baseline (984.321 us; speedup 1.0000x reference)
//
#include <hip/hip_runtime.h>
#include <hip/hip_bf16.h>

#define NSEQ  256
#define VOCAB 32000
#define HID   4096
#define OUTL  128
#define CAP   4096
#define NBINS 8192

typedef float v4f __attribute__((ext_vector_type(4)));
typedef short v8s __attribute__((ext_vector_type(8)));

__device__ __forceinline__ unsigned fkey(float f){
  unsigned u = __float_as_uint(f);
  return (u & 0x80000000u) ? ~u : (u | 0x80000000u);
}

// f32 -> bf16 round-to-nearest-even, on raw bits
__device__ __forceinline__ unsigned short f2bf(float f){
  unsigned u = __float_as_uint(f);
  u += 0x7fffu + ((u >> 16) & 1u);
  return (unsigned short)(u >> 16);
}
__device__ __forceinline__ float bf2f(unsigned short s){
  return __uint_as_float(((unsigned)s) << 16);
}
__device__ __forceinline__ unsigned pack2(unsigned short lo, unsigned short hi){
  return (unsigned)lo | ((unsigned)hi << 16);
}

// ---------------- split hidden into bf16 hi/lo (RTN) ----------------
__global__ __launch_bounds__(256)
void split_hidden(const float* __restrict__ hid,
                  unsigned int* __restrict__ hh,
                  unsigned int* __restrict__ hl){
  int i = blockIdx.x * 256 + threadIdx.x;          // float4 index, 262144 total
  v4f v = ((const v4f*)hid)[i];
  unsigned short h0 = f2bf(v.x), h1 = f2bf(v.y), h2 = f2bf(v.z), h3 = f2bf(v.w);
  unsigned short l0 = f2bf(v.x - bf2f(h0));
  unsigned short l1 = f2bf(v.y - bf2f(h1));
  unsigned short l2 = f2bf(v.z - bf2f(h2));
  unsigned short l3 = f2bf(v.w - bf2f(h3));
  hh[i*2+0] = pack2(h0, h1);
  hh[i*2+1] = pack2(h2, h3);
  hl[i*2+0] = pack2(l0, l1);
  hl[i*2+1] = pack2(l2, l3);
}

// ---------------- GEMM: logits = hid @ emb^T + bias (3-product bf16 split) ----
__global__ __launch_bounds__(256, 2)
void gemm_logits(const float* __restrict__ emb,
                 const unsigned short* __restrict__ hh,
                 const unsigned short* __restrict__ hl,
                 const float* __restrict__ bias,
                 float* __restrict__ out){
  const int bt = blockIdx.x;     // 0..1   (b tile of 128)
  const int vt = blockIdx.y;     // 0..249 (v tile of 128)
  const int tid = threadIdx.x;
  const int lane = tid & 63;
  const int wid = tid >> 6;
  const int wr = wid >> 1;       // b half
  const int wc = wid & 1;        // v half

  __shared__ unsigned short lds_hh[128*64];
  __shared__ unsigned short lds_hl[128*64];
  __shared__ unsigned short lds_eh[128*64];
  __shared__ unsigned short lds_el[128*64];

  v4f acc[4][4];
  #pragma unroll
  for (int m=0;m<4;m++)
    #pragma unroll
    for (int n=0;n<4;n++) acc[m][n] = (v4f){0.f,0.f,0.f,0.f};

  const int frow = lane & 15;
  const int fk   = (lane >> 4) * 8;

  for (int k0 = 0; k0 < HID; k0 += 64){
    // ---- stage hid tiles (pre-split bf16): 128 rows x 64 cols = 1024 chunks of 8
    #pragma unroll
    for (int it=0; it<4; ++it){                  // FIX: was it<2 (only staged rows 0..63)
      int c   = it*256 + tid;          // 1024 x 16B chunks
      int row = c >> 3;                // 0..127
      int col = (c & 7) * 8;
      size_t g = (size_t)(bt*128 + row) * HID + k0 + col;
      v8s vh = *(const v8s*)(hh + g);
      v8s vl = *(const v8s*)(hl + g);
      int e = (row*64 + col) ^ ((row & 7) << 3);   // T2 XOR swizzle
      *(v8s*)(lds_hh + e) = vh;
      *(v8s*)(lds_hl + e) = vl;
    }
    // ---- stage emb tile (fp32 -> bf16 hi/lo, RTN) ----
    #pragma unroll
    for (int it=0; it<8; ++it){
      int c   = it*256 + tid;          // 2048 x float4 chunks
      int row = c >> 4;
      int col = (c & 15) * 4;
      v4f v = *(const v4f*)(emb + (size_t)(vt*128 + row) * HID + k0 + col);
      unsigned short h0 = f2bf(v.x), h1 = f2bf(v.y), h2 = f2bf(v.z), h3 = f2bf(v.w);
      unsigned short l0 = f2bf(v.x - bf2f(h0));
      unsigned short l1 = f2bf(v.y - bf2f(h1));
      unsigned short l2 = f2bf(v.z - bf2f(h2));
      unsigned short l3 = f2bf(v.w - bf2f(h3));
      int e = (row*64 + col) ^ ((row & 7) << 3);
      *(uint2*)(lds_eh + e) = make_uint2(pack2(h0, h1), pack2(h2, h3));
      *(uint2*)(lds_el + e) = make_uint2(pack2(l0, l1), pack2(l2, l3));
    }
    __syncthreads();
    // ---- compute ----
    #pragma unroll
    for (int kk=0; kk<2; ++kk){
      v8s Ah[4], Al[4], Bh[4], Bl[4];
      #pragma unroll
      for (int m=0;m<4;m++){
        int row = wr*64 + m*16 + frow;
        int e = (row*64 + kk*32 + fk) ^ ((row & 7) << 3);
        Ah[m] = *(const v8s*)(lds_hh + e);
        Al[m] = *(const v8s*)(lds_hl + e);
      }
      #pragma unroll
      for (int n=0;n<4;n++){
        int row = wc*64 + n*16 + frow;
        int e = (row*64 + kk*32 + fk) ^ ((row & 7) << 3);
        Bh[n] = *(const v8s*)(lds_eh + e);
        Bl[n] = *(const v8s*)(lds_el + e);
      }
      #pragma unroll
      for (int m=0;m<4;m++)
        #pragma unroll
        for (int n=0;n<4;n++){
          acc[m][n] = __builtin_amdgcn_mfma_f32_16x16x32_bf16(Ah[m], Bh[n], acc[m][n], 0, 0, 0);
          acc[m][n] = __builtin_amdgcn_mfma_f32_16x16x32_bf16(Ah[m], Bl[n], acc[m][n], 0, 0, 0);
          acc[m][n] = __builtin_amdgcn_mfma_f32_16x16x32_bf16(Al[m], Bh[n], acc[m][n], 0, 0, 0);
        }
    }
    __syncthreads();
  }
  // ---- epilogue: bias + store ----
  #pragma unroll
  for (int n=0;n<4;n++){
    int col = vt*128 + wc*64 + n*16 + (lane & 15);
    float bv = bias[col];
    #pragma unroll
    for (int m=0;m<4;m++){
      int rowb = bt*128 + wr*64 + m*16 + (lane >> 4)*4;
      #pragma unroll
      for (int r=0;r<4;r++)
        out[(size_t)(rowb + r)*VOCAB + col] = acc[m][n][r] + bv;
    }
  }
}

// ---------------- presence/frequency penalties ----------------
__global__ __launch_bounds__(OUTL)
void apply_penalties(const int* __restrict__ toks,
                     const float* __restrict__ pres,
                     const float* __restrict__ freq,
                     float* __restrict__ logits){
  const int row = blockIdx.x;
  const int i = threadIdx.x;
  __shared__ int t[OUTL];
  const int tok = toks[row*OUTL + i];
  t[i] = tok;
  __syncthreads();
  bool first = true;
  for (int j = 0; j < i; ++j) if (t[j] == tok) { first = false; break; }
  float sub = freq[row] + (first ? pres[row] : 0.0f);
  atomicAdd(&logits[(size_t)row*VOCAB + tok], -sub);
}

// ---------------- per-row stats: max, Z, k-th-largest bin, candidate collect ----
__global__ __launch_bounds__(512)
void row_stats(const float* __restrict__ logits,
               const float* __restrict__ temps,
               const int* __restrict__ topks,
               float* __restrict__ rm, float* __restrict__ rz,
               int* __restrict__ rn,
               unsigned long long* __restrict__ cand){
  const int row = blockIdx.x;
  const int tid = threadIdx.x;
  const float* lp = logits + (size_t)row * VOCAB;

  __shared__ unsigned int hist[NBINS];          // 32 KB
  __shared__ float sred[8];
  __shared__ float s_m, s_z;
  __shared__ int s_tbin, s_cnt;

  // pass 1: row max
  float mx = -3.4e38f;
  for (int i = tid; i < VOCAB/4; i += 512){
    v4f v = ((const v4f*)lp)[i];
    mx = fmaxf(fmaxf(mx, v.x), fmaxf(fmaxf(v.y, v.z), v.w));
  }
  #pragma unroll
  for (int off=32; off; off>>=1) mx = fmaxf(mx, __shfl_down(mx, off));
  if ((tid & 63) == 0) sred[tid>>6] = mx;
  __syncthreads();
  if (tid == 0){
    float m = sred[0];
    for (int w=1; w<8; w++) m = fmaxf(m, sred[w]);
    s_m = m;
  }
  for (int i = tid; i < NBINS; i += 512) hist[i] = 0;
  __syncthreads();
  const float m = s_m;
  const float invT = 1.0f / temps[row];

  // pass 2: Z + histogram of sortable float keys
  float z = 0.f;
  for (int i = tid; i < VOCAB/4; i += 512){
    v4f v = ((const v4f*)lp)[i];
    z += __expf((v.x - m)*invT); atomicAdd(&hist[fkey(v.x)>>19], 1u);
    z += __expf((v.y - m)*invT); atomicAdd(&hist[fkey(v.y)>>19], 1u);
    z += __expf((v.z - m)*invT); atomicAdd(&hist[fkey(v.z)>>19], 1u);
    z += __expf((v.w - m)*invT); atomicAdd(&hist[fkey(v.w)>>19], 1u);
  }
  #pragma unroll
  for (int off=32; off; off>>=1) z += __shfl_down(z, off);
  if ((tid & 63) == 0) sred[tid>>6] = z;
  __syncthreads();
  if (tid == 0){
    float zz = 0.f;
    for (int w=0; w<8; w++) zz += sred[w];
    s_z = zz;
    int k = topks[row]; if (k < 1) k = 1; if (k > CAP) k = CAP;
    int cum = 0; int b = NBINS - 1;
    for (; b > 0; --b){ cum += (int)hist[b]; if (cum >= k) break; }
    s_tbin = b;
    s_cnt = 0;
  }
  __syncthreads();
  const int tbin = s_tbin;

  // pass 3: collect candidates (key ordered, stable by index)
  for (int i = tid; i < VOCAB; i += 512){
    unsigned key = fkey(lp[i]);
    if ((int)(key >> 19) >= tbin){
      int p = atomicAdd(&s_cnt, 1);
      if (p < CAP)
        cand[(size_t)row*CAP + p] = ((unsigned long long)key << 32) | (unsigned)(~i);
    }
  }
  __syncthreads();
  if (tid == 0){ rm[row] = m; rz[row] = s_z; rn[row] = (s_cnt < CAP) ? s_cnt : CAP; }
}

// ---------------- sort candidates, apply top-k/top-p, renormalize ----------------
__global__ __launch_bounds__(1024)
void topk_mask(unsigned long long* __restrict__ cand,
               const float* __restrict__ rm, const float* __restrict__ rz,
               const int* __restrict__ rn,
               const float* __restrict__ temps,
               const float* __restrict__ topps, const int* __restrict__ topks){
  const int row = blockIdx.x;
  const int tid = threadIdx.x;
  __shared__ unsigned long long s[CAP];          // 32 KB
  __shared__ float tsum[1024];
  __shared__ float sred[16];
  __shared__ float s_S;

  const int n = rn[row];
  unsigned long long* cp = cand + (size_t)row*CAP;
  for (int i = tid; i < CAP; i += 1024) s[i] = (i < n) ? cp[i] : 0ULL;
  __syncthreads();

  // bitonic sort, descending
  for (int k = 2; k <= CAP; k <<= 1){
    for (int j = k >> 1; j > 0; j >>= 1){
      #pragma unroll 4
      for (int t = tid; t < CAP; t += 1024){
        int l = t ^ j;
        if (l > t){
          unsigned long long a = s[t], b = s[l];
          bool up = ((t & k) == 0);
          if (up ? (a < b) : (a > b)){ s[t] = b; s[l] = a; }
        }
      }
      __syncthreads();
    }
  }

  const float m = rm[row], Z = rz[row];
  const float invT = 1.0f / temps[row];
  const float limit = topps[row] * Z;
  const int tk = topks[row];

  // per-thread 4 consecutive sorted elements
  const int base = tid * 4;
  float pv[4];
  float loc = 0.f;
  #pragma unroll
  for (int q=0;q<4;q++){
    int i = base + q;
    float p = 0.f;
    if (i < n){
      unsigned key = (unsigned)(s[i] >> 32);
      unsigned u = (key & 0x80000000u) ? (key & 0x7fffffffu) : ~key;
      p = __expf((__uint_as_float(u) - m) * invT);
    }
    pv[q] = p; loc += p;
  }
  tsum[tid] = loc;
  __syncthreads();
  // Hillis-Steele inclusive scan over thread sums
  for (int off = 1; off < 1024; off <<= 1){
    float v = (tid >= off) ? tsum[tid - off] : 0.f;
    __syncthreads();
    tsum[tid] += v;
    __syncthreads();
  }
  float excl = (tid == 0) ? 0.f : tsum[tid - 1];

  float keepP = 0.f;
  int keepf[4];
  #pragma unroll
  for (int q=0;q<4;q++){
    int i = base + q;
    bool keep = (i < n) && (i < tk) && (excl <= limit);
    keepf[q] = keep;
    if (keep) keepP += pv[q];
    excl += pv[q];
  }
  #pragma unroll
  for (int off=32; off; off>>=1) keepP += __shfl_down(keepP, off);
  if ((tid & 63) == 0) sred[tid>>6] = keepP;
  __syncthreads();
  if (tid == 0){
    float ss = 0.f;
    for (int w=0; w<16; w++) ss += sred[w];
    s_S = ss;
  }
  __syncthreads();
  const float rS = 1.0f / s_S;

  #pragma unroll
  for (int q=0;q<4;q++){
    int i = base + q;
    if (i < n){
      unsigned idx = ~(unsigned)(s[i] & 0xffffffffu);
      float val = keepf[q] ? pv[q] * rS : 0.f;
      cp[i] = ((unsigned long long)idx << 32) | __float_as_uint(val);
    }
  }
}

// ---------------- zero output, scatter kept probs ----------------
__global__ __launch_bounds__(256)
void zero_out(float* __restrict__ out){
  long i = (long)blockIdx.x * 256 + threadIdx.x;   // float4 index
  if (i < (long)NSEQ*VOCAB/4) ((v4f*)out)[i] = (v4f){0.f,0.f,0.f,0.f};
}

__global__ __launch_bounds__(256)
void scatter_out(const unsigned long long* __restrict__ cand,
                 const int* __restrict__ rn,
                 float* __restrict__ out){
  const int row = blockIdx.x;
  const int n = rn[row];
  for (int i = threadIdx.x; i < n; i += 256){
    unsigned long long e = cand[(size_t)row*CAP + i];
    out[(size_t)row*VOCAB + (unsigned)(e >> 32)] = __uint_as_float((unsigned)e);
  }
}

extern "C" void kernel_launch(void* const* d_in, const int* in_sizes, int n_in,
                              void* d_out, int out_size, void* d_ws, size_t ws_size,
                              hipStream_t stream){
  const float* hid  = (const float*)d_in[0];
  const float* emb  = (const float*)d_in[1];
  const float* bias = (const float*)d_in[2];
  const int*   toks = (const int*)d_in[3];
  const float* pres = (const float*)d_in[4];
  const float* freq = (const float*)d_in[5];
  const float* temp = (const float*)d_in[6];
  const float* topp = (const float*)d_in[7];
  const int*   topk = (const int*)d_in[8];
  float* out = (float*)d_out;

  char* ws = (char*)d_ws;
  unsigned int*   hh32 = (unsigned int*)ws;                       // 2 MB
  unsigned int*   hl32 = (unsigned int*)(ws + (2u<<20));          // 2 MB
  float* rm = (float*)(ws + (4u<<20));
  float* rz = (float*)(ws + (4u<<20) + 4096);
  int*   rn = (int*)  (ws + (4u<<20) + 8192);
  unsigned long long* cand = (unsigned long long*)(ws + (4u<<20) + 16384); // 8 MB

  split_hidden<<<1024, 256, 0, stream>>>(hid, hh32, hl32);
  gemm_logits<<<dim3(2, VOCAB/128), 256, 0, stream>>>(
      emb, (const unsigned short*)hh32, (const unsigned short*)hl32, bias, out);
  apply_penalties<<<NSEQ, OUTL, 0, stream>>>(toks, pres, freq, out);
  row_stats<<<NSEQ, 512, 0, stream>>>(out, temp, topk, rm, rz, rn, cand);
  topk_mask<<<NSEQ, 1024, 0, stream>>>(cand, rm, rz, rn, temp, topp, topk);
  zero_out<<<(NSEQ*VOCAB/4 + 255)/256, 256, 0, stream>>>(out);
  scatter_out<<<NSEQ, 256, 0, stream>>>(cand, rn, out);
}